// Round 4
// baseline (126.201 us; speedup 1.0000x reference)
//
#include <hip/hip_runtime.h>
#include <math.h>

#define NQ 10
#define WW 113
#define BB 16
#define CC 22
#define NF 8
#define FDIM 352   // CC*NF*2
#define NS (BB*WW) // 1808
#define NGATE 23
#define SLOT(j) ((j) ^ (((j) >> 5) & 31))

#define WAVE_FENCE() do { \
    asm volatile("s_waitcnt lgkmcnt(0)" ::: "memory"); \
    __builtin_amdgcn_sched_barrier(0); \
} while (0)

__device__ __forceinline__ float2 cmul(float2 a, float2 b) {
    return make_float2(a.x*b.x - a.y*b.y, a.x*b.y + a.y*b.x);
}

// ---------------- gate table (static circuit structure) -------------------
__constant__ int G_KIND[NGATE]  = {0,0,0,0,0, 0,0,0,0, 1,1,1,1,1, 0,0,0,0, 1,1, 0,0, 1};
__constant__ int G_LAYER[NGATE] = {0,0,0,0,0, 0,0,0,0, 0,0,0,0,0, 1,1,1,1, 1,1, 2,2, 2};
__constant__ int G_IA[NGATE]    = {0,2,4,6,8, 1,3,5,7, 0,1,2,3,4, 0,2,1,3, 0,1, 0,1, 0};

__device__ void u3mat(float2* U, float th, float ph, float lm) {
    float ct, st, cp, sp, cl, sl;
    sincosf(th * 0.5f, &st, &ct);
    sincosf(ph, &sp, &cp);
    sincosf(lm, &sl, &cl);
    U[0] = make_float2(ct, 0.f);
    U[1] = make_float2(-cl * st, -sl * st);
    U[2] = make_float2(cp * st, sp * st);
    U[3] = make_float2((cp * cl - sp * sl) * ct, (sp * cl + cp * sl) * ct);
}

__device__ void mm4(float2* C, const float2* A, const float2* B) {
#pragma unroll
    for (int i = 0; i < 4; ++i)
#pragma unroll
        for (int j = 0; j < 4; ++j) {
            float2 acc = make_float2(0.f, 0.f);
#pragma unroll
            for (int k = 0; k < 4; ++k) {
                float2 p = cmul(A[i*4+k], B[k*4+j]);
                acc.x += p.x; acc.y += p.y;
            }
            C[i*4+j] = acc;
        }
}

// prep: gate matrices + softmax weights + zero out
__global__ __launch_bounds__(64) void prep_kernel(
    const float* __restrict__ conv,   // (3,10,15)
    const float* __restrict__ pool,   // (3,5,3)
    const float* __restrict__ aggw,   // (113,)
    float2* __restrict__ mats,        // (23,16)
    float* __restrict__ wts,          // (113,)
    float* __restrict__ out)          // (16,) -> zeroed
{
    const int t = threadIdx.x;

    float a0 = (t < WW) ? aggw[t] : -1e30f;
    float a1 = (t + 64 < WW) ? aggw[t + 64] : -1e30f;
    float mx = fmaxf(a0, a1);
    for (int off = 32; off > 0; off >>= 1) mx = fmaxf(mx, __shfl_xor(mx, off));
    float e0 = (t < WW) ? expf(a0 - mx) : 0.f;
    float e1 = (t + 64 < WW) ? expf(a1 - mx) : 0.f;
    float es = e0 + e1;
    for (int off = 32; off > 0; off >>= 1) es += __shfl_xor(es, off);
    float inv = 1.0f / es;
    if (t < WW) wts[t] = e0 * inv;
    if (t + 64 < WW) wts[t + 64] = e1 * inv;
    if (t < BB) out[t] = 0.f;

    if (t >= NGATE) return;
    int kind = G_KIND[t], layer = G_LAYER[t], ia = G_IA[t];
    float2 F[16];
    if (kind == 0) {
        const float* wp = conv + layer * 150;
        float2 Uw0[4], Un0[4], Uw1[4], Un1[4];
        u3mat(Uw0, wp[ia*15+0], wp[ia*15+1], wp[ia*15+2]);
        u3mat(Un0, wp[(ia+1)*15+3], wp[(ia+1)*15+4], wp[(ia+1)*15+5]);
        u3mat(Uw1, wp[ia*15+9], wp[ia*15+10], wp[ia*15+11]);
        u3mat(Un1, wp[(ia+1)*15+12], wp[(ia+1)*15+13], wp[(ia+1)*15+14]);
        float2 Kpre[16], Kpost[16];
#pragma unroll
        for (int a = 0; a < 2; ++a)
#pragma unroll
        for (int b = 0; b < 2; ++b)
#pragma unroll
        for (int c = 0; c < 2; ++c)
#pragma unroll
        for (int d = 0; d < 2; ++d) {
            Kpre [(2*a+b)*4 + (2*c+d)] = cmul(Uw0[a*2+c], Un0[b*2+d]);
            Kpost[(2*a+b)*4 + (2*c+d)] = cmul(Uw1[a*2+c], Un1[b*2+d]);
        }
        float cz, sz, cy, sy, cx, sx;
        sincosf(wp[ia*15+6] * 0.5f, &sz, &cz);
        sincosf(wp[ia*15+7] * 0.5f, &sy, &cy);
        sincosf(wp[ia*15+8] * 0.5f, &sx, &cx);
        float2 Z[16], Y[16], X[16];
#pragma unroll
        for (int k = 0; k < 16; ++k) { Z[k] = make_float2(0,0); Y[k] = make_float2(0,0); X[k] = make_float2(0,0); }
        Z[0]  = make_float2(cz, -sz); Z[5]  = make_float2(cz, sz);
        Z[10] = make_float2(cz,  sz); Z[15] = make_float2(cz, -sz);
        Y[0] = Y[5] = Y[10] = Y[15] = make_float2(cy, 0);
        Y[0*4+3] = make_float2(0,  sy); Y[1*4+2] = make_float2(0, -sy);
        Y[2*4+1] = make_float2(0, -sy); Y[3*4+0] = make_float2(0,  sy);
        X[0] = X[5] = X[10] = X[15] = make_float2(cx, 0);
        X[0*4+3] = X[1*4+2] = X[2*4+1] = X[3*4+0] = make_float2(0, -sx);
        float2 T1[16], M[16], T2[16];
        mm4(T1, Y, Z);
        mm4(M, X, T1);
        mm4(T2, M, Kpre);
        mm4(F, Kpost, T2);
    } else {
        const float* pp = pool + layer * 15 + ia * 3;
        float2 U[4];
        u3mat(U, pp[0], pp[1], pp[2]);
#pragma unroll
        for (int k = 0; k < 16; ++k) F[k] = make_float2(0,0);
        F[0*4+0] = make_float2(1,0); F[1*4+1] = make_float2(1,0);
        F[2*4+2] = U[0]; F[2*4+3] = U[1];
        F[3*4+2] = U[2]; F[3*4+3] = U[3];
    }
#pragma unroll
    for (int k = 0; k < 16; ++k) mats[t*16 + k] = F[k];
}

// ---------------- register-state helpers ----------------------------------
template<int B3,int B2,int B1,int B0>
__device__ __forceinline__ int lanepart(int L) {
    constexpr int rm = (1<<B3)|(1<<B2)|(1<<B1)|(1<<B0);
    int idx = 0, lb = 5;
#pragma unroll
    for (int p = 9; p >= 0; --p)
        if (!((rm >> p) & 1)) { idx |= ((L >> lb) & 1) << p; --lb; }
    return idx;
}

template<int B3,int B2,int B1,int B0>
__device__ __forceinline__ int rpart(int r) {
    return (((r>>3)&1)<<B3) | (((r>>2)&1)<<B2) | (((r>>1)&1)<<B1) | ((r&1)<<B0);
}

// gate on register-nibble bit positions PA (wire/high of 4x4 index), PB (low)
template<int PA, int PB>
__device__ __forceinline__ void rgate(float2* amp, const float2* __restrict__ m)
{
    constexpr int mask = (1<<PA) | (1<<PB);
#pragma unroll
    for (int base = 0; base < 16; ++base) {
        if (base & mask) continue;
        float2 a0 = amp[base];
        float2 a1 = amp[base | (1<<PB)];
        float2 a2 = amp[base | (1<<PA)];
        float2 a3 = amp[base | mask];
        float2 nn[4];
#pragma unroll
        for (int g = 0; g < 4; ++g) {
            float2 m0 = m[g*4+0], m1 = m[g*4+1], m2 = m[g*4+2], m3 = m[g*4+3];
            float rx, ry;
            rx = m0.x*a0.x;            rx = fmaf(-m0.y, a0.y, rx);
            rx = fmaf(m1.x, a1.x, rx); rx = fmaf(-m1.y, a1.y, rx);
            rx = fmaf(m2.x, a2.x, rx); rx = fmaf(-m2.y, a2.y, rx);
            rx = fmaf(m3.x, a3.x, rx); rx = fmaf(-m3.y, a3.y, rx);
            ry = m0.x*a0.y;            ry = fmaf(m0.y, a0.x, ry);
            ry = fmaf(m1.x, a1.y, ry); ry = fmaf(m1.y, a1.x, ry);
            ry = fmaf(m2.x, a2.y, ry); ry = fmaf(m2.y, a2.x, ry);
            ry = fmaf(m3.x, a3.y, ry); ry = fmaf(m3.y, a3.x, ry);
            nn[g] = make_float2(rx, ry);
        }
        amp[base]           = nn[0];
        amp[base | (1<<PB)] = nn[1];
        amp[base | (1<<PA)] = nn[2];
        amp[base | mask]    = nn[3];
    }
}

// re-layout state between register-bit partitions through per-wave LDS
template<int O3,int O2,int O1,int O0, int N3,int N2,int N1,int N0>
__device__ __forceinline__ void relayout(float2* wst, float2* amp, int L)
{
    const int lo = lanepart<O3,O2,O1,O0>(L);
#pragma unroll
    for (int r = 0; r < 16; ++r) {
        int idx = lo | rpart<O3,O2,O1,O0>(r);
        wst[SLOT(idx)] = amp[r];
    }
    WAVE_FENCE();
    const int ln = lanepart<N3,N2,N1,N0>(L);
#pragma unroll
    for (int r = 0; r < 16; ++r) {
        int idx = ln | rpart<N3,N2,N1,N0>(r);
        amp[r] = wst[SLOT(idx)];
    }
    WAVE_FENCE();
}

// ---------------- fused feature + circuit + aggregate kernel --------------
__global__ __launch_bounds__(256) void fused_kernel(
    const float* __restrict__ x,           // (16,22,128)
    const float* __restrict__ proj_w,      // (10,352)
    const float* __restrict__ proj_b,      // (10,)
    const float* __restrict__ freq_scale,  // (10,)
    const float2* __restrict__ mats,       // (23,16)
    const float* __restrict__ wts,         // (113,)
    float* __restrict__ out)               // (16,)
{
    const int tid  = threadIdx.x;
    const int wave = tid >> 6;
    const int L    = tid & 63;
    const int s = blockIdx.x * 4 + wave;
    const int b = s / WW, w = s % WW;

    __shared__ float2 wst_all[4][1024];   // 32 KB, one 8KB region per wave
    float2* wst = wst_all[wave];

    // ---- feature phase (all inside this wave's LDS region) ----
    float*  win  = (float*)wst;           // floats [0,352)
    float*  feat = (float*)wst + 384;     // floats [384,736)
    float2* tw   = wst + 400;             // float2 [400,416)
    float2* vq   = wst + 416;             // float2 [416,436)
    float*  angs = (float*)wst + 880;     // floats [880,890)

    const float* xb = x + b * (CC * 128) + w;
    for (int e = L; e < CC * 16; e += 64) {
        int c = e >> 4, n = e & 15;
        win[e] = xb[c * 128 + n];
    }
    if (L < 16) {
        float ang = -(float)M_PI * (float)L * 0.125f;
        float sv, cv; sincosf(ang, &sv, &cv);
        tw[L] = make_float2(cv, sv);
    }
    WAVE_FENCE();

    // DFT features: 176 points (c,k), 3 strided passes
    for (int pidx = L; pidx < CC * NF; pidx += 64) {
        int c = pidx >> 3, k = pidx & 7;
        float re = 0.f, im = 0.f;
#pragma unroll
        for (int n = 0; n < 16; ++n) {
            int m = (k * n) & 15;
            float2 t = tw[m];
            float xv = win[c * 16 + n];
            re = fmaf(xv, t.x, re);
            im = fmaf(xv, t.y, im);
        }
        feat[c * 16 + (k << 1)]     = log1pf(sqrtf(re * re + im * im));
        feat[c * 16 + (k << 1) + 1] = atan2f(im, re) * (float)(1.0 / M_PI);
    }
    WAVE_FENCE();

    // projection: 10 dots of length 352
    {
        float fv[6];
#pragma unroll
        for (int k = 0; k < 6; ++k) {
            int e = L + 64 * k;
            fv[k] = (e < FDIM) ? feat[e] : 0.f;
        }
        for (int q = 0; q < NQ; ++q) {
            const float* pw = proj_w + q * FDIM + L;
            float acc = 0.f;
#pragma unroll
            for (int k = 0; k < 6; ++k) {
                float wv = (L + 64 * k < FDIM) ? pw[64 * k] : 0.f;
                acc = fmaf(fv[k], wv, acc);
            }
#pragma unroll
            for (int off = 32; off > 0; off >>= 1) acc += __shfl_xor(acc, off);
            if (L == 0) angs[q] = acc;
        }
    }
    WAVE_FENCE();

    if (L < NQ) {
        float a = tanhf(angs[L] + proj_b[L]) * (float)M_PI;
        float bf = freq_scale[L] * a;
        float ca, sa, cb, sb;
        sincosf(a * 0.5f, &sa, &ca);
        sincosf(bf * 0.5f, &sb, &cb);
        vq[2 * L]     = make_float2(cb * ca, -sb * sa);   // qubit L, bit=0
        vq[2 * L + 1] = make_float2(cb * sa, -sb * ca);   // qubit L, bit=1
    }
    WAVE_FENCE();

    // ---- init in partition A {9,8,7,6}: lane L = idx[5:0], r = idx[9:6] ----
    float2 amp[16];
    {
        float2 pre = make_float2(1.f, 0.f);
#pragma unroll
        for (int p = 0; p < 6; ++p) {
            float2 f = vq[2 * (9 - p) + ((L >> p) & 1)];
            pre = cmul(pre, f);
        }
        float2 p98[4], p76[4];
#pragma unroll
        for (int i = 0; i < 4; ++i) {
            p98[i] = cmul(vq[2 * 0 + (i >> 1)], vq[2 * 1 + (i & 1)]); // bits 9,8
            p76[i] = cmul(vq[2 * 2 + (i >> 1)], vq[2 * 3 + (i & 1)]); // bits 7,6
        }
#pragma unroll
        for (int r = 0; r < 16; ++r)
            amp[r] = cmul(pre, cmul(p98[r >> 2], p76[r & 3]));
    }
    WAVE_FENCE();

    // ---- 6 rounds of register gates + 5 re-layouts ----
    // Round A {9,8,7,6}: (9,8)m0 (7,6)m1 (8,7)m5 (8,9)p m9
    rgate<3,2>(amp, mats + 0*16);
    rgate<1,0>(amp, mats + 1*16);
    rgate<2,1>(amp, mats + 5*16);
    rgate<2,3>(amp, mats + 9*16);
    relayout<9,8,7,6, 5,4,3,2>(wst, amp, L);
    // Round B {5,4,3,2}: (5,4)m2 (3,2)m3 (4,3)m7
    rgate<3,2>(amp, mats + 2*16);
    rgate<1,0>(amp, mats + 3*16);
    rgate<2,1>(amp, mats + 7*16);
    relayout<5,4,3,2, 7,6,5,4>(wst, amp, L);
    // Round C1 {7,6,5,4}: (6,5)m6 (6,7)p m10 (4,5)p m11
    rgate<2,1>(amp, mats + 6*16);
    rgate<2,3>(amp, mats + 10*16);
    rgate<0,1>(amp, mats + 11*16);
    relayout<7,6,5,4, 3,2,1,0>(wst, amp, L);
    // Round C2 {3,2,1,0}: (1,0)m4 (2,1)m8 (2,3)p m12 (0,1)p m13
    rgate<1,0>(amp, mats + 4*16);
    rgate<2,1>(amp, mats + 8*16);
    rgate<2,3>(amp, mats + 12*16);
    rgate<0,1>(amp, mats + 13*16);
    relayout<3,2,1,0, 9,7,5,3>(wst, amp, L);
    // Round D0 {9,7,5,3}: (9,7)m14 (5,3)m15 (7,5)m16 (7,9)p m18
    rgate<3,2>(amp, mats + 14*16);
    rgate<1,0>(amp, mats + 15*16);
    rgate<2,1>(amp, mats + 16*16);
    rgate<2,3>(amp, mats + 18*16);
    relayout<9,7,5,3, 9,5,3,1>(wst, amp, L);
    // Round D1 {9,5,3,1}: (3,1)m17 (3,5)p m19 (9,5)m20 (5,1)m21 (5,9)p m22
    rgate<1,0>(amp, mats + 17*16);
    rgate<1,2>(amp, mats + 19*16);
    rgate<3,2>(amp, mats + 20*16);
    rgate<2,0>(amp, mats + 21*16);
    rgate<2,3>(amp, mats + 22*16);

    // ---- measurement: bit 9 (qubit 0) sits at register-nibble bit 3 ----
    float local = 0.f;
#pragma unroll
    for (int r = 0; r < 16; ++r) {
        float p = amp[r].x * amp[r].x + amp[r].y * amp[r].y;
        local += (r & 8) ? -p : p;
    }
#pragma unroll
    for (int off = 32; off > 0; off >>= 1) local += __shfl_xor(local, off);
    if (L == 0) atomicAdd(&out[b], local * wts[w]);
}

extern "C" void kernel_launch(void* const* d_in, const int* in_sizes, int n_in,
                              void* d_out, int out_size, void* d_ws, size_t ws_size,
                              hipStream_t stream)
{
    const float* x           = (const float*)d_in[0];
    const float* proj_w      = (const float*)d_in[1];
    const float* proj_b      = (const float*)d_in[2];
    const float* freq_scale  = (const float*)d_in[3];
    const float* conv_params = (const float*)d_in[4];
    const float* pool_params = (const float*)d_in[5];
    const float* aggw        = (const float*)d_in[6];
    float* out = (float*)d_out;

    float2* mats = (float2*)d_ws;                 // 23*16 float2
    float* wts   = (float*)d_ws + NGATE * 16 * 2; // 113 floats

    prep_kernel<<<1, 64, 0, stream>>>(conv_params, pool_params, aggw, mats, wts, out);
    fused_kernel<<<NS / 4, 256, 0, stream>>>(x, proj_w, proj_b, freq_scale, mats, wts, out);
}